// Round 2
// baseline (430.641 us; speedup 1.0000x reference)
//
#include <hip/hip_runtime.h>
#include <cstdint>
#include <math.h>

#define NB 128  // batch size

// ---------------------------------------------------------------------------
// Weight packing: w [O, C, KH, KW] fp32 -> wp [O, KH*KW, C/32] bitwords,
// bit (c%32) of word = (w[o][c][kh][kw] >= 0)
// ---------------------------------------------------------------------------
__global__ void pack_w_kernel(const float* __restrict__ w, uint32_t* __restrict__ wp,
                              int O, int C, int KHW) {
  int i = blockIdx.x * 256 + threadIdx.x;
  int Cw = C >> 5;
  int total = O * KHW * Cw;
  if (i >= total) return;
  int cw = i % Cw;
  int rest = i / Cw;
  int t = rest % KHW;
  int o = rest / KHW;
  uint32_t word = 0;
  for (int b = 0; b < 32; ++b) {
    float v = w[(o * C + cw * 32 + b) * KHW + t];
    word |= (v >= 0.0f ? 1u : 0u) << b;
  }
  wp[i] = word;
}

// ---------------------------------------------------------------------------
// Conv1: fp32 input x [128,3,32,32], sign(w1) [128,3,3,3], pad=1.
// DOUBLE accumulation: downstream layers are chaotic in the sign bits, so
// conv1 must match the float64 numpy reference essentially exactly.
// Emits packed sign bits of bn1 output: out [128,32,32,4] (bit = channel sign)
// ---------------------------------------------------------------------------
__global__ __launch_bounds__(256) void conv1_kernel(
    const float* __restrict__ x, const float* __restrict__ w1,
    const float* __restrict__ bs, const float* __restrict__ bt,
    uint32_t* __restrict__ out) {
  const int ocw = blockIdx.y;
  __shared__ float wlds[27 * 32];   // +-1.0f
  __shared__ float sl[32], tl[32];
  for (int i = threadIdx.x; i < 27 * 32; i += 256) {
    int oc = i & 31, k = i >> 5;
    float v = w1[(ocw * 32 + oc) * 27 + k];
    wlds[k * 32 + oc] = (v >= 0.0f) ? 1.0f : -1.0f;
  }
  if (threadIdx.x < 32) {
    sl[threadIdx.x] = bs[ocw * 32 + threadIdx.x];
    tl[threadIdx.x] = bt[ocw * 32 + threadIdx.x];
  }
  __syncthreads();
  int p = blockIdx.x * 256 + threadIdx.x;  // p = (n*32+y)*32+x, exact grid
  int px = p & 31, py = (p >> 5) & 31, n = p >> 10;
  double acc[32];
#pragma unroll
  for (int oc = 0; oc < 32; ++oc) acc[oc] = 0.0;
  for (int ic = 0; ic < 3; ++ic) {
    for (int kh = 0; kh < 3; ++kh) {
      int yy = py + kh - 1;
      if ((unsigned)yy >= 32u) continue;
      for (int kw = 0; kw < 3; ++kw) {
        int xx = px + kw - 1;
        if ((unsigned)xx >= 32u) continue;
        double xv = (double)x[((n * 3 + ic) * 32 + yy) * 32 + xx];
        int k = ic * 9 + kh * 3 + kw;
#pragma unroll
        for (int oc = 0; oc < 32; ++oc) {
          // wlds is +-1: add or subtract (exact)
          acc[oc] += (wlds[k * 32 + oc] >= 0.0f) ? xv : -xv;
        }
      }
    }
  }
  uint32_t word = 0;
#pragma unroll
  for (int oc = 0; oc < 32; ++oc) {
    double v = acc[oc] * (double)sl[oc] + (double)tl[oc];
    word |= (v >= 0.0 ? 1u : 0u) << oc;
  }
  out[p * 4 + ocw] = word;
}

// ---------------------------------------------------------------------------
// Binary conv 3x3 pad=1: act [NB,H,W,CW] bitwords -> out [NB,H,W,OCW] bitwords
// dot = 32*n_valid_words - 2*popcount(xor)  (exact integer)
// sign decision in DOUBLE: s*dot is exact (24b x 14b mantissa), single
// rounded add of t -> bit-identical to a float64 numpy reference.
// ---------------------------------------------------------------------------
template <int CW, int H, int W>
__global__ __launch_bounds__(256) void bconv_kernel(
    const uint32_t* __restrict__ act, const uint32_t* __restrict__ wp,
    const float* __restrict__ bs, const float* __restrict__ bt,
    uint32_t* __restrict__ out, int OCW) {
  const int ocw = blockIdx.y;
  __shared__ __align__(16) uint32_t wlds[9 * CW * 32];
  __shared__ float sl[32], tl[32];
  for (int i = threadIdx.x; i < 9 * CW * 32; i += 256) {
    int oc = i & 31, tcw = i >> 5;
    wlds[i] = wp[(ocw * 32 + oc) * (9 * CW) + tcw];  // wlds[tcw*32+oc]
  }
  if (threadIdx.x < 32) {
    sl[threadIdx.x] = bs[ocw * 32 + threadIdx.x];
    tl[threadIdx.x] = bt[ocw * 32 + threadIdx.x];
  }
  __syncthreads();
  int p = blockIdx.x * 256 + threadIdx.x;
  if (p >= NB * H * W) return;
  int px = p % W, py = (p / W) % H, n = p / (H * W);
  int acc[32];
#pragma unroll
  for (int oc = 0; oc < 32; ++oc) acc[oc] = 0;
  int nv = 0;
  for (int kh = 0; kh < 3; ++kh) {
    int yy = py + kh - 1;
    if ((unsigned)yy >= (unsigned)H) continue;
    for (int kw = 0; kw < 3; ++kw) {
      int xx = px + kw - 1;
      if ((unsigned)xx >= (unsigned)W) continue;
      const uint32_t* arow = act + ((n * H + yy) * W + xx) * CW;
      int tap = kh * 3 + kw;
      nv += CW;
      for (int cw = 0; cw < CW; ++cw) {
        uint32_t a = arow[cw];
        const uint4* w4 = reinterpret_cast<const uint4*>(&wlds[(tap * CW + cw) * 32]);
#pragma unroll
        for (int q = 0; q < 8; ++q) {
          uint4 wv = w4[q];
          acc[q * 4 + 0] += __popc(a ^ wv.x);
          acc[q * 4 + 1] += __popc(a ^ wv.y);
          acc[q * 4 + 2] += __popc(a ^ wv.z);
          acc[q * 4 + 3] += __popc(a ^ wv.w);
        }
      }
    }
  }
  uint32_t word = 0;
#pragma unroll
  for (int oc = 0; oc < 32; ++oc) {
    double dotd = (double)(32 * nv - 2 * acc[oc]);
    double v = dotd * (double)sl[oc] + (double)tl[oc];
    word |= (v >= 0.0 ? 1u : 0u) << oc;
  }
  out[p * OCW + ocw] = word;
}

// ---------------------------------------------------------------------------
// 2x2 maxpool on sign bits == OR of the 4 pixel bitwords
// (sign(bn(max(v))) == OR_i sign(bn(v_i)) since s>0 and s*v+t monotone in v)
// ---------------------------------------------------------------------------
__global__ void pool_or_kernel(const uint32_t* __restrict__ in, uint32_t* __restrict__ out,
                               int HO, int WO, int CW) {
  int i = blockIdx.x * 256 + threadIdx.x;
  int total = NB * HO * WO * CW;
  if (i >= total) return;
  int cw = i % CW;
  int r = i / CW;
  int xo = r % WO; r /= WO;
  int yo = r % HO; int n = r / HO;
  int WI = WO * 2;
  const uint32_t* base = in + (((size_t)n * (HO * 2) + yo * 2) * WI + xo * 2) * CW + cw;
  out[i] = base[0] | base[CW] | base[(size_t)WI * CW] | base[(size_t)WI * CW + CW];
}

// ---------------------------------------------------------------------------
// Conv7 (4x4 VALID, K=512*16=8192 = 256 words) + bn7 + log_softmax (double)
// One block (1 wave) per image.
// ---------------------------------------------------------------------------
__global__ __launch_bounds__(64) void conv7_kernel(
    const uint32_t* __restrict__ act, const uint32_t* __restrict__ wp,
    const float* __restrict__ bs, const float* __restrict__ bt,
    float* __restrict__ out) {
  int n = blockIdx.x;
  int lane = threadIdx.x;
  const uint32_t* a = act + n * 256;
  __shared__ double logits[10];
  for (int o = 0; o < 10; ++o) {
    int acc = 0;
    for (int w = lane; w < 256; w += 64) acc += __popc(a[w] ^ wp[o * 256 + w]);
    for (int off = 32; off > 0; off >>= 1) acc += __shfl_down(acc, off, 64);
    if (lane == 0) {
      double dotd = (double)(8192 - 2 * acc);
      logits[o] = dotd * (double)bs[o] + (double)bt[o];
    }
  }
  __syncthreads();
  if (lane == 0) {
    double m = logits[0];
    for (int o = 1; o < 10; ++o) m = fmax(m, logits[o]);
    double s = 0.0;
    for (int o = 0; o < 10; ++o) s += exp(logits[o] - m);
    double lse = log(s);
    for (int o = 0; o < 10; ++o) out[n * 10 + o] = (float)(logits[o] - m - lse);
  }
}

// ---------------------------------------------------------------------------
extern "C" void kernel_launch(void* const* d_in, const int* in_sizes, int n_in,
                              void* d_out, int out_size, void* d_ws, size_t ws_size,
                              hipStream_t stream) {
  const float* x  = (const float*)d_in[0];
  const float* w1 = (const float*)d_in[1];
  const float* w2 = (const float*)d_in[2];
  const float* w3 = (const float*)d_in[3];
  const float* w4 = (const float*)d_in[4];
  const float* w5 = (const float*)d_in[5];
  const float* w6 = (const float*)d_in[6];
  const float* w7 = (const float*)d_in[7];
  // bn params: d_in[8+2i] = s, d_in[9+2i] = t  (i = layer-1)
  const float* s1 = (const float*)d_in[8];  const float* t1 = (const float*)d_in[9];
  const float* s2 = (const float*)d_in[10]; const float* t2 = (const float*)d_in[11];
  const float* s3 = (const float*)d_in[12]; const float* t3 = (const float*)d_in[13];
  const float* s4 = (const float*)d_in[14]; const float* t4 = (const float*)d_in[15];
  const float* s5 = (const float*)d_in[16]; const float* t5 = (const float*)d_in[17];
  const float* s6 = (const float*)d_in[18]; const float* t6 = (const float*)d_in[19];
  const float* s7 = (const float*)d_in[20]; const float* t7 = (const float*)d_in[21];
  float* out = (float*)d_out;

  uint32_t* ws = (uint32_t*)d_ws;
  uint32_t* A   = ws;                 // 524288 words (2 MB) ping
  uint32_t* B   = ws + 524288;        // 524288 words pong
  uint32_t* wp2 = ws + 1048576;       // 128*9*4   = 4608
  uint32_t* wp3 = wp2 + 4608;         // 256*9*4   = 9216
  uint32_t* wp4 = wp3 + 9216;         // 256*9*8   = 18432
  uint32_t* wp5 = wp4 + 18432;        // 512*9*8   = 36864
  uint32_t* wp6 = wp5 + 36864;        // 512*9*16  = 73728
  uint32_t* wp7 = wp6 + 73728;        // 10*16*16  = 2560   (total ~4.8 MB)

  // --- pack weights (ws is re-poisoned every call; must repack each time) ---
  {
    struct { const float* w; uint32_t* wp; int O, C, KHW; } jobs[6] = {
      {w2, wp2, 128, 128, 9}, {w3, wp3, 256, 128, 9}, {w4, wp4, 256, 256, 9},
      {w5, wp5, 512, 256, 9}, {w6, wp6, 512, 512, 9}, {w7, wp7, 10, 512, 16},
    };
    for (int j = 0; j < 6; ++j) {
      int total = jobs[j].O * jobs[j].KHW * (jobs[j].C >> 5);
      pack_w_kernel<<<dim3((total + 255) / 256), dim3(256), 0, stream>>>(
          jobs[j].w, jobs[j].wp, jobs[j].O, jobs[j].C, jobs[j].KHW);
    }
  }

  // L1: conv1(f64 acc) + bn1 + sign -> A [128,32,32,4]
  conv1_kernel<<<dim3(512, 4), dim3(256), 0, stream>>>(x, w1, s1, t1, A);

  // L2: bconv (CW=4, 32x32, OC=128) A->B ; pool-OR B->A [128,16,16,4]
  bconv_kernel<4, 32, 32><<<dim3(512, 4), dim3(256), 0, stream>>>(A, wp2, s2, t2, B, 4);
  pool_or_kernel<<<dim3(512), dim3(256), 0, stream>>>(B, A, 16, 16, 4);

  // L3: bconv (CW=4, 16x16, OC=256) A->B [128,16,16,8]
  bconv_kernel<4, 16, 16><<<dim3(128, 8), dim3(256), 0, stream>>>(A, wp3, s3, t3, B, 8);

  // L4: bconv (CW=8, 16x16, OC=256) B->A ; pool-OR A->B [128,8,8,8]
  bconv_kernel<8, 16, 16><<<dim3(128, 8), dim3(256), 0, stream>>>(B, wp4, s4, t4, A, 8);
  pool_or_kernel<<<dim3(256), dim3(256), 0, stream>>>(A, B, 8, 8, 8);

  // L5: bconv (CW=8, 8x8, OC=512) B->A [128,8,8,16]
  bconv_kernel<8, 8, 8><<<dim3(32, 16), dim3(256), 0, stream>>>(B, wp5, s5, t5, A, 16);

  // L6: bconv (CW=16, 8x8, OC=512) A->B ; pool-OR B->A [128,4,4,16]
  bconv_kernel<16, 8, 8><<<dim3(32, 16), dim3(256), 0, stream>>>(A, wp6, s6, t6, B, 16);
  pool_or_kernel<<<dim3(128), dim3(256), 0, stream>>>(B, A, 4, 4, 16);

  // L7: conv7 + bn7 + log_softmax -> out [128,10]
  conv7_kernel<<<dim3(128), dim3(64), 0, stream>>>(A, wp7, s7, t7, out);
}

// Round 3
// 420.385 us; speedup vs baseline: 1.0244x; 1.0244x over previous
//
#include <hip/hip_runtime.h>
#include <cstdint>
#include <math.h>

#define NB 128  // batch size

// ---------------------------------------------------------------------------
// Fused weight packing for all binarized layers.
// Layers 2-6 (3x3 convs): NEW layout wp[ocw][tap][cw][oc32] so the 32 weight
// words consumed together are contiguous -> s_load_dwordx16 in bconv.
// Layer 7 (4x4): OLD layout wp[o][tap][cw] (conv7 consumes it linearly).
// bit (c%32) of word = (w[o][c][kh][kw] >= 0)
// ---------------------------------------------------------------------------
__global__ void pack_all_kernel(
    const float* __restrict__ w2, const float* __restrict__ w3,
    const float* __restrict__ w4, const float* __restrict__ w5,
    const float* __restrict__ w6, const float* __restrict__ w7,
    uint32_t* __restrict__ wp2, uint32_t* __restrict__ wp3,
    uint32_t* __restrict__ wp4, uint32_t* __restrict__ wp5,
    uint32_t* __restrict__ wp6, uint32_t* __restrict__ wp7) {
  int i = blockIdx.x * 256 + threadIdx.x;
  const float* w; uint32_t* wp; int C, KHW; bool nl = true;
  if (i < 4608)        { w = w2; wp = wp2; C = 128; KHW = 9; }
  else if (i < 13824)  { i -= 4608;   w = w3; wp = wp3; C = 128; KHW = 9; }
  else if (i < 32256)  { i -= 13824;  w = w4; wp = wp4; C = 256; KHW = 9; }
  else if (i < 69120)  { i -= 32256;  w = w5; wp = wp5; C = 256; KHW = 9; }
  else if (i < 142848) { i -= 69120;  w = w6; wp = wp6; C = 512; KHW = 9; }
  else if (i < 145408) { i -= 142848; w = w7; wp = wp7; C = 512; KHW = 16; nl = false; }
  else return;
  int Cw = C >> 5;
  int cw = i % Cw;
  int rest = i / Cw;
  int t = rest % KHW;
  int o = rest / KHW;
  uint32_t word = 0;
  for (int b = 0; b < 32; ++b)
    word |= ((w[(o * C + cw * 32 + b) * KHW + t] >= 0.0f) ? 1u : 0u) << b;
  if (nl) wp[(((o >> 5) * KHW + t) * Cw + cw) * 32 + (o & 31)] = word;
  else    wp[(o * KHW + t) * Cw + cw] = word;
}

// ---------------------------------------------------------------------------
// Conv1: fp32 input x [128,3,32,32], sign(w1) [128,3,3,3], pad=1.
// DOUBLE accumulation: downstream layers are chaotic in the sign bits, so
// conv1 must match the float64 numpy reference essentially exactly.
// Emits packed sign bits of bn1 output: out [128,32,32,4]
// ---------------------------------------------------------------------------
__global__ __launch_bounds__(256) void conv1_kernel(
    const float* __restrict__ x, const float* __restrict__ w1,
    const float* __restrict__ bs, const float* __restrict__ bt,
    uint32_t* __restrict__ out) {
  const int ocw = blockIdx.y;
  __shared__ float wlds[27 * 32];   // +-1.0f
  __shared__ float sl[32], tl[32];
  for (int i = threadIdx.x; i < 27 * 32; i += 256) {
    int oc = i & 31, k = i >> 5;
    float v = w1[(ocw * 32 + oc) * 27 + k];
    wlds[k * 32 + oc] = (v >= 0.0f) ? 1.0f : -1.0f;
  }
  if (threadIdx.x < 32) {
    sl[threadIdx.x] = bs[ocw * 32 + threadIdx.x];
    tl[threadIdx.x] = bt[ocw * 32 + threadIdx.x];
  }
  __syncthreads();
  int p = blockIdx.x * 256 + threadIdx.x;  // exact grid
  int px = p & 31, py = (p >> 5) & 31, n = p >> 10;
  double acc[32];
#pragma unroll
  for (int oc = 0; oc < 32; ++oc) acc[oc] = 0.0;
  for (int ic = 0; ic < 3; ++ic) {
    for (int kh = 0; kh < 3; ++kh) {
      int yy = py + kh - 1;
      if ((unsigned)yy >= 32u) continue;
      for (int kw = 0; kw < 3; ++kw) {
        int xx = px + kw - 1;
        if ((unsigned)xx >= 32u) continue;
        double xv = (double)x[((n * 3 + ic) * 32 + yy) * 32 + xx];
        int k = ic * 9 + kh * 3 + kw;
#pragma unroll
        for (int oc = 0; oc < 32; ++oc)
          acc[oc] += (wlds[k * 32 + oc] >= 0.0f) ? xv : -xv;
      }
    }
  }
  uint32_t word = 0;
#pragma unroll
  for (int oc = 0; oc < 32; ++oc) {
    double v = acc[oc] * (double)sl[oc] + (double)tl[oc];
    word |= (v >= 0.0 ? 1u : 0u) << oc;
  }
  out[p * 4 + ocw] = word;
}

// ---------------------------------------------------------------------------
// Binary conv 3x3 pad=1, zero LDS. Weights are wave-uniform -> read through
// the scalar path (s_load) from the [ocw][tap][cw][oc32] layout; act row in
// VGPRs; inner op is v_xor(s-operand) + accumulating v_bcnt.
// dot = 32*nv - 2*popc; sign in double (exact: s*dot is 24b x <=14b mantissa).
// POOL: fused 2x2 OR-pool via shfl_xor (lanes: xor 1 = col pair, xor W = row
// pair; wave base is a multiple of 64 so row parity is lane-aligned).
// ---------------------------------------------------------------------------
template <int CW, int H, int W, bool POOL>
__global__ __launch_bounds__(256) void bconv_kernel(
    const uint32_t* __restrict__ act, const uint32_t* __restrict__ wp,
    const float* __restrict__ bs, const float* __restrict__ bt,
    uint32_t* __restrict__ out, int OCW) {
  const int ocw = blockIdx.y;
  const int p = blockIdx.x * 256 + threadIdx.x;  // exact grid, no bounds check
  const int px = p % W, py = (p / W) % H, n = p / (H * W);
  int acc[32];
#pragma unroll
  for (int oc = 0; oc < 32; ++oc) acc[oc] = 0;
  int nv = 0;
#pragma unroll
  for (int kh = 0; kh < 3; ++kh) {
#pragma unroll
    for (int kw = 0; kw < 3; ++kw) {
      const int tap = kh * 3 + kw;
      const uint32_t* wtap = wp + (ocw * 9 + tap) * CW * 32;  // uniform
      const int yy = py + kh - 1, xx = px + kw - 1;
      const bool valid = ((unsigned)yy < (unsigned)H) && ((unsigned)xx < (unsigned)W);
      uint32_t av[CW];
      if (valid) {
        const uint32_t* arow = act + ((n * H + yy) * W + xx) * CW;
#pragma unroll
        for (int cw = 0; cw < CW; ++cw) av[cw] = arow[cw];
        nv += CW;
      }
#pragma unroll
      for (int cw = 0; cw < CW; ++cw) {
        const uint32_t* wrow = wtap + cw * 32;  // uniform address
        uint32_t wv[32];
#pragma unroll
        for (int oc = 0; oc < 32; ++oc) wv[oc] = wrow[oc];  // uniform control -> s_load
        if (valid) {
#pragma unroll
          for (int oc = 0; oc < 32; ++oc) acc[oc] += __popc(av[cw] ^ wv[oc]);
        }
      }
    }
  }
  uint32_t word = 0;
#pragma unroll
  for (int oc = 0; oc < 32; ++oc) {
    double dotd = (double)(32 * nv - 2 * acc[oc]);
    double v = dotd * (double)bs[ocw * 32 + oc] + (double)bt[ocw * 32 + oc];
    word |= (v >= 0.0 ? 1u : 0u) << oc;
  }
  if (!POOL) {
    out[p * OCW + ocw] = word;
  } else {
    uint32_t o2 = word | __shfl_xor(word, 1, 64);
    uint32_t o4 = o2 | __shfl_xor(o2, W, 64);
    if (((px | py) & 1) == 0) {
      const int xo = px >> 1, yo = py >> 1;
      out[((n * (H / 2) + yo) * (W / 2) + xo) * OCW + ocw] = o4;
    }
  }
}

// ---------------------------------------------------------------------------
// Conv7 (4x4 VALID, K=512*16=8192 = 256 words) + bn7 + log_softmax (double)
// One block (1 wave) per image.
// ---------------------------------------------------------------------------
__global__ __launch_bounds__(64) void conv7_kernel(
    const uint32_t* __restrict__ act, const uint32_t* __restrict__ wp,
    const float* __restrict__ bs, const float* __restrict__ bt,
    float* __restrict__ out) {
  int n = blockIdx.x;
  int lane = threadIdx.x;
  const uint32_t* a = act + n * 256;
  __shared__ double logits[10];
  for (int o = 0; o < 10; ++o) {
    int acc = 0;
    for (int w = lane; w < 256; w += 64) acc += __popc(a[w] ^ wp[o * 256 + w]);
    for (int off = 32; off > 0; off >>= 1) acc += __shfl_down(acc, off, 64);
    if (lane == 0) {
      double dotd = (double)(8192 - 2 * acc);
      logits[o] = dotd * (double)bs[o] + (double)bt[o];
    }
  }
  __syncthreads();
  if (lane == 0) {
    double m = logits[0];
    for (int o = 1; o < 10; ++o) m = fmax(m, logits[o]);
    double s = 0.0;
    for (int o = 0; o < 10; ++o) s += exp(logits[o] - m);
    double lse = log(s);
    for (int o = 0; o < 10; ++o) out[n * 10 + o] = (float)(logits[o] - m - lse);
  }
}

// ---------------------------------------------------------------------------
extern "C" void kernel_launch(void* const* d_in, const int* in_sizes, int n_in,
                              void* d_out, int out_size, void* d_ws, size_t ws_size,
                              hipStream_t stream) {
  const float* x  = (const float*)d_in[0];
  const float* w1 = (const float*)d_in[1];
  const float* w2 = (const float*)d_in[2];
  const float* w3 = (const float*)d_in[3];
  const float* w4 = (const float*)d_in[4];
  const float* w5 = (const float*)d_in[5];
  const float* w6 = (const float*)d_in[6];
  const float* w7 = (const float*)d_in[7];
  const float* s1 = (const float*)d_in[8];  const float* t1 = (const float*)d_in[9];
  const float* s2 = (const float*)d_in[10]; const float* t2 = (const float*)d_in[11];
  const float* s3 = (const float*)d_in[12]; const float* t3 = (const float*)d_in[13];
  const float* s4 = (const float*)d_in[14]; const float* t4 = (const float*)d_in[15];
  const float* s5 = (const float*)d_in[16]; const float* t5 = (const float*)d_in[17];
  const float* s6 = (const float*)d_in[18]; const float* t6 = (const float*)d_in[19];
  const float* s7 = (const float*)d_in[20]; const float* t7 = (const float*)d_in[21];
  float* out = (float*)d_out;

  uint32_t* ws = (uint32_t*)d_ws;
  uint32_t* A   = ws;                 // 524288 words (2 MB) ping
  uint32_t* B   = ws + 524288;        // 524288 words pong
  uint32_t* wp2 = ws + 1048576;       // 128*9*4   = 4608
  uint32_t* wp3 = wp2 + 4608;         // 256*9*4   = 9216
  uint32_t* wp4 = wp3 + 9216;         // 256*9*8   = 18432
  uint32_t* wp5 = wp4 + 18432;        // 512*9*8   = 36864
  uint32_t* wp6 = wp5 + 36864;        // 512*9*16  = 73728
  uint32_t* wp7 = wp6 + 73728;        // 10*16*16  = 2560

  // pack all weights in one dispatch (ws re-poisoned every call -> repack)
  pack_all_kernel<<<dim3(568), dim3(256), 0, stream>>>(
      w2, w3, w4, w5, w6, w7, wp2, wp3, wp4, wp5, wp6, wp7);

  // L1: conv1(f64 acc) + bn1 + sign -> A [128,32,32,4]
  conv1_kernel<<<dim3(512, 4), dim3(256), 0, stream>>>(x, w1, s1, t1, A);

  // L2: bconv+pool (CW=4, 32x32) A->B [128,16,16,4]
  bconv_kernel<4, 32, 32, true><<<dim3(512, 4), dim3(256), 0, stream>>>(A, wp2, s2, t2, B, 4);

  // L3: bconv (CW=4, 16x16, OC=256) B->A [128,16,16,8]
  bconv_kernel<4, 16, 16, false><<<dim3(128, 8), dim3(256), 0, stream>>>(B, wp3, s3, t3, A, 8);

  // L4: bconv+pool (CW=8, 16x16) A->B [128,8,8,8]
  bconv_kernel<8, 16, 16, true><<<dim3(128, 8), dim3(256), 0, stream>>>(A, wp4, s4, t4, B, 8);

  // L5: bconv (CW=8, 8x8, OC=512) B->A [128,8,8,16]
  bconv_kernel<8, 8, 8, false><<<dim3(32, 16), dim3(256), 0, stream>>>(B, wp5, s5, t5, A, 16);

  // L6: bconv+pool (CW=16, 8x8) A->B [128,4,4,16]
  bconv_kernel<16, 8, 8, true><<<dim3(32, 16), dim3(256), 0, stream>>>(A, wp6, s6, t6, B, 16);

  // L7: conv7 + bn7 + log_softmax -> out [128,10]
  conv7_kernel<<<dim3(128), dim3(64), 0, stream>>>(B, wp7, s7, t7, out);
}

// Round 4
// 328.806 us; speedup vs baseline: 1.3097x; 1.2785x over previous
//
#include <hip/hip_runtime.h>
#include <cstdint>
#include <math.h>

#define NB 128  // batch size

// ---------------------------------------------------------------------------
// Weight packing.
// Layers 2-6: layout wp[ocg][tap][cw][oc64]  (oc64 = lane) so a wave's 64
//   weight words per (tap,cw) are one coalesced dword load.
// Layer 7:    layout wp[o][tap][cw] (conv7 consumes linearly).
// bit (c%32) of word = (w[o][c][kh][kw] >= 0)
// ---------------------------------------------------------------------------
__global__ void pack_all_kernel(
    const float* __restrict__ w2, const float* __restrict__ w3,
    const float* __restrict__ w4, const float* __restrict__ w5,
    const float* __restrict__ w6, const float* __restrict__ w7,
    uint32_t* __restrict__ wp2, uint32_t* __restrict__ wp3,
    uint32_t* __restrict__ wp4, uint32_t* __restrict__ wp5,
    uint32_t* __restrict__ wp6, uint32_t* __restrict__ wp7) {
  int i = blockIdx.x * 256 + threadIdx.x;
  const float* w; uint32_t* wp; int C, KHW; bool nl = true;
  if (i < 4608)        { w = w2; wp = wp2; C = 128; KHW = 9; }
  else if (i < 13824)  { i -= 4608;   w = w3; wp = wp3; C = 128; KHW = 9; }
  else if (i < 32256)  { i -= 13824;  w = w4; wp = wp4; C = 256; KHW = 9; }
  else if (i < 69120)  { i -= 32256;  w = w5; wp = wp5; C = 256; KHW = 9; }
  else if (i < 142848) { i -= 69120;  w = w6; wp = wp6; C = 512; KHW = 9; }
  else if (i < 145408) { i -= 142848; w = w7; wp = wp7; C = 512; KHW = 16; nl = false; }
  else return;
  int Cw = C >> 5;
  int cw = i % Cw;
  int rest = i / Cw;
  int t = rest % KHW;
  int o = rest / KHW;
  uint32_t word = 0;
  for (int b = 0; b < 32; ++b)
    word |= ((w[(o * C + cw * 32 + b) * KHW + t] >= 0.0f) ? 1u : 0u) << b;
  if (nl) wp[(((o >> 6) * KHW + t) * Cw + cw) * 64 + (o & 63)] = word;
  else    wp[(o * KHW + t) * Cw + cw] = word;
}

// ---------------------------------------------------------------------------
// Conv1: fp32 input x [128,3,32,32], sign(w1) [128,3,3,3], pad=1.
// DOUBLE accumulation (must match float64 numpy reference; downstream is
// chaotic in the sign bits). out [128,32,32,4] packed sign bits.
// ---------------------------------------------------------------------------
__global__ __launch_bounds__(256) void conv1_kernel(
    const float* __restrict__ x, const float* __restrict__ w1,
    const float* __restrict__ bs, const float* __restrict__ bt,
    uint32_t* __restrict__ out) {
  const int ocw = blockIdx.y;
  __shared__ float wlds[27 * 32];   // +-1.0f
  __shared__ float sl[32], tl[32];
  for (int i = threadIdx.x; i < 27 * 32; i += 256) {
    int oc = i & 31, k = i >> 5;
    float v = w1[(ocw * 32 + oc) * 27 + k];
    wlds[k * 32 + oc] = (v >= 0.0f) ? 1.0f : -1.0f;
  }
  if (threadIdx.x < 32) {
    sl[threadIdx.x] = bs[ocw * 32 + threadIdx.x];
    tl[threadIdx.x] = bt[ocw * 32 + threadIdx.x];
  }
  __syncthreads();
  int p = blockIdx.x * 256 + threadIdx.x;  // exact grid
  int px = p & 31, py = (p >> 5) & 31, n = p >> 10;
  double acc[32];
#pragma unroll
  for (int oc = 0; oc < 32; ++oc) acc[oc] = 0.0;
  for (int ic = 0; ic < 3; ++ic) {
    for (int kh = 0; kh < 3; ++kh) {
      int yy = py + kh - 1;
      if ((unsigned)yy >= 32u) continue;
      for (int kw = 0; kw < 3; ++kw) {
        int xx = px + kw - 1;
        if ((unsigned)xx >= 32u) continue;
        double xv = (double)x[((n * 3 + ic) * 32 + yy) * 32 + xx];
        int k = ic * 9 + kh * 3 + kw;
#pragma unroll
        for (int oc = 0; oc < 32; ++oc)
          acc[oc] += (wlds[k * 32 + oc] >= 0.0f) ? xv : -xv;
      }
    }
  }
  uint32_t word = 0;
#pragma unroll
  for (int oc = 0; oc < 32; ++oc) {
    double v = acc[oc] * (double)sl[oc] + (double)tl[oc];
    word |= (v >= 0.0 ? 1u : 0u) << oc;
  }
  out[p * 4 + ocw] = word;
}

// ---------------------------------------------------------------------------
// Binary conv 3x3 pad=1 — "oc-in-lane, weight-stationary" formulation.
//   lane  = output channel within the wave's 64-oc group (blockIdx.y)
//   block = 1 wave = a chunk of R rows x PC cols of pixels for one image
// Weights: wp[ocg][tap][cw][oc64] -> 9*CW lane-private VGPRs, loaded ONCE.
// Activations: wave-uniform addresses -> scalar loads (K$), no LDS, no VMEM
//   in the hot loop. Inner op: v_xor(s_act, v_w) + accumulating v_bcnt.
// Border taps: wave-uniform branches (skipped entirely, not exec-masked).
// Epilogue: sign of bn in f64 (exact: s*dot has 24b x <=14b mantissas);
//   __ballot packs 64 lanes' sign bits = 2 output words per pixel.
//   POOL (R must be 2, PC even): OR of the 4 ballots of each 2x2 quad.
// ---------------------------------------------------------------------------
template <int CW, int H, int W, int PC, int R, bool POOL, int MINW>
__global__ __launch_bounds__(64, MINW) void bconv_kernel(
    const uint32_t* __restrict__ act, const uint32_t* __restrict__ wpk,
    const float* __restrict__ bs, const float* __restrict__ bt,
    uint32_t* __restrict__ out, int OCW) {
  const int lane = threadIdx.x;
  const int ocg = blockIdx.y;
  // chunk decomposition: blockIdx.x = ((n * (H/R)) + rg) * (W/PC) + cg
  const int cpr = W / PC;           // chunks per row-group
  const int c = blockIdx.x;
  const int cg = c % cpr;
  const int rg = (c / cpr) % (H / R);
  const int n  = c / (cpr * (H / R));
  const int y0 = rg * R, x0 = cg * PC;

  // --- stationary weights: 9*CW lane-private words, coalesced load ---
  uint32_t wreg[9 * CW];
#pragma unroll
  for (int t = 0; t < 9; ++t)
#pragma unroll
    for (int cw = 0; cw < CW; ++cw)
      wreg[t * CW + cw] = wpk[(((ocg * 9) + t) * CW + cw) * 64 + lane];

  int acc[R * PC];
#pragma unroll
  for (int p = 0; p < R * PC; ++p) acc[p] = 0;

  // --- main loop: iterate act rows/cols once, scatter into pixel accs ---
#pragma unroll
  for (int ry = -1; ry <= R; ++ry) {
    const int y = y0 + ry;
    if (y < 0 || y >= H) continue;          // uniform branch
#pragma unroll
    for (int cc = -1; cc <= PC; ++cc) {
      const int x = x0 + cc;
      if (x < 0 || x >= W) continue;        // uniform branch
      const uint32_t* ap = act + ((n * H + y) * W + x) * CW;
      uint32_t av[CW];
#pragma unroll
      for (int cw = 0; cw < CW; ++cw) av[cw] = ap[cw];  // uniform -> s_load
#pragma unroll
      for (int r = 0; r < R; ++r) {
        const int kh = ry - r + 1;          // compile-time after unroll
        if (kh < 0 || kh > 2) continue;
#pragma unroll
        for (int kw = 0; kw < 3; ++kw) {
          const int pxo = cc - kw + 1;      // compile-time
          if (pxo < 0 || pxo >= PC) continue;
#pragma unroll
          for (int cw = 0; cw < CW; ++cw)
            acc[r * PC + pxo] += __popc(av[cw] ^ wreg[(kh * 3 + kw) * CW + cw]);
        }
      }
    }
  }

  // --- epilogue: bn sign (f64, exact) -> ballot-packed words ---
  const double sd = (double)bs[ocg * 64 + lane];
  const double td = (double)bt[ocg * 64 + lane];
  if (!POOL) {
    uint64_t bal[R * PC];
#pragma unroll
    for (int r = 0; r < R; ++r)
#pragma unroll
      for (int pxo = 0; pxo < PC; ++pxo) {
        const int y = y0 + r, x = x0 + pxo;
        const int nv = CW * (3 - (y == 0) - (y == H - 1)) * (3 - (x == 0) - (x == W - 1));
        double v = (double)(32 * nv - 2 * acc[r * PC + pxo]) * sd + td;
        bal[r * PC + pxo] = __ballot(v >= 0.0);
      }
    if (lane == 0) {
#pragma unroll
      for (int r = 0; r < R; ++r)
#pragma unroll
        for (int pxo = 0; pxo < PC; ++pxo) {
          uint32_t* o = out + ((n * H + (y0 + r)) * W + (x0 + pxo)) * OCW + ocg * 2;
          uint64_t m = bal[r * PC + pxo];
          o[0] = (uint32_t)m; o[1] = (uint32_t)(m >> 32);
        }
    }
  } else {
    static_assert(!POOL || R == 2, "pool needs row pairs");
    uint64_t pooled[PC / 2];
#pragma unroll
    for (int c2 = 0; c2 < PC / 2; ++c2) pooled[c2] = 0;
#pragma unroll
    for (int r = 0; r < R; ++r)
#pragma unroll
      for (int pxo = 0; pxo < PC; ++pxo) {
        const int y = y0 + r, x = x0 + pxo;
        const int nv = CW * (3 - (y == 0) - (y == H - 1)) * (3 - (x == 0) - (x == W - 1));
        double v = (double)(32 * nv - 2 * acc[r * PC + pxo]) * sd + td;
        pooled[pxo >> 1] |= __ballot(v >= 0.0);
      }
    if (lane == 0) {
#pragma unroll
      for (int c2 = 0; c2 < PC / 2; ++c2) {
        const int yo = y0 >> 1, xo = (x0 >> 1) + c2;
        uint32_t* o = out + ((n * (H / 2) + yo) * (W / 2) + xo) * OCW + ocg * 2;
        o[0] = (uint32_t)pooled[c2]; o[1] = (uint32_t)(pooled[c2] >> 32);
      }
    }
  }
}

// ---------------------------------------------------------------------------
// Conv7 (4x4 VALID, K=512*16=8192 = 256 words) + bn7 + log_softmax (double)
// One block (1 wave) per image.
// ---------------------------------------------------------------------------
__global__ __launch_bounds__(64) void conv7_kernel(
    const uint32_t* __restrict__ act, const uint32_t* __restrict__ wp,
    const float* __restrict__ bs, const float* __restrict__ bt,
    float* __restrict__ out) {
  int n = blockIdx.x;
  int lane = threadIdx.x;
  const uint32_t* a = act + n * 256;
  __shared__ double logits[10];
  for (int o = 0; o < 10; ++o) {
    int acc = 0;
    for (int w = lane; w < 256; w += 64) acc += __popc(a[w] ^ wp[o * 256 + w]);
    for (int off = 32; off > 0; off >>= 1) acc += __shfl_down(acc, off, 64);
    if (lane == 0) {
      double dotd = (double)(8192 - 2 * acc);
      logits[o] = dotd * (double)bs[o] + (double)bt[o];
    }
  }
  __syncthreads();
  if (lane == 0) {
    double m = logits[0];
    for (int o = 1; o < 10; ++o) m = fmax(m, logits[o]);
    double s = 0.0;
    for (int o = 0; o < 10; ++o) s += exp(logits[o] - m);
    double lse = log(s);
    for (int o = 0; o < 10; ++o) out[n * 10 + o] = (float)(logits[o] - m - lse);
  }
}

// ---------------------------------------------------------------------------
extern "C" void kernel_launch(void* const* d_in, const int* in_sizes, int n_in,
                              void* d_out, int out_size, void* d_ws, size_t ws_size,
                              hipStream_t stream) {
  const float* x  = (const float*)d_in[0];
  const float* w1 = (const float*)d_in[1];
  const float* w2 = (const float*)d_in[2];
  const float* w3 = (const float*)d_in[3];
  const float* w4 = (const float*)d_in[4];
  const float* w5 = (const float*)d_in[5];
  const float* w6 = (const float*)d_in[6];
  const float* w7 = (const float*)d_in[7];
  const float* s1 = (const float*)d_in[8];  const float* t1 = (const float*)d_in[9];
  const float* s2 = (const float*)d_in[10]; const float* t2 = (const float*)d_in[11];
  const float* s3 = (const float*)d_in[12]; const float* t3 = (const float*)d_in[13];
  const float* s4 = (const float*)d_in[14]; const float* t4 = (const float*)d_in[15];
  const float* s5 = (const float*)d_in[16]; const float* t5 = (const float*)d_in[17];
  const float* s6 = (const float*)d_in[18]; const float* t6 = (const float*)d_in[19];
  const float* s7 = (const float*)d_in[20]; const float* t7 = (const float*)d_in[21];
  float* out = (float*)d_out;

  uint32_t* ws = (uint32_t*)d_ws;
  uint32_t* A   = ws;                 // 524288 words (2 MB) ping
  uint32_t* B   = ws + 524288;        // 524288 words pong
  uint32_t* wp2 = ws + 1048576;       // 2*9*4*64   = 4608
  uint32_t* wp3 = wp2 + 4608;         // 4*9*4*64   = 9216
  uint32_t* wp4 = wp3 + 9216;         // 4*9*8*64   = 18432
  uint32_t* wp5 = wp4 + 18432;        // 8*9*8*64   = 36864
  uint32_t* wp6 = wp5 + 36864;        // 8*9*16*64  = 73728
  uint32_t* wp7 = wp6 + 73728;        // 10*16*16   = 2560

  // pack all weights in one dispatch (ws re-poisoned every call -> repack)
  pack_all_kernel<<<dim3(568), dim3(256), 0, stream>>>(
      w2, w3, w4, w5, w6, w7, wp2, wp3, wp4, wp5, wp6, wp7);

  // L1: conv1(f64 acc) + bn1 + sign -> A [128,32,32,4]
  conv1_kernel<<<dim3(512, 4), dim3(256), 0, stream>>>(x, w1, s1, t1, A);

  // L2: bconv+pool (CW=4, 32x32) A->B [128,16,16,4]   grid 128*16*4=8192 x 2
  bconv_kernel<4, 32, 32, 8, 2, true, 4>
      <<<dim3(8192, 2), dim3(64), 0, stream>>>(A, wp2, s2, t2, B, 4);

  // L3: bconv (CW=4, 16x16, OC=256) B->A [128,16,16,8]  grid 128*16=2048 x 4
  bconv_kernel<4, 16, 16, 16, 1, false, 4>
      <<<dim3(2048, 4), dim3(64), 0, stream>>>(B, wp3, s3, t3, A, 8);

  // L4: bconv+pool (CW=8, 16x16) A->B [128,8,8,8]      grid 128*8*2=2048 x 4
  bconv_kernel<8, 16, 16, 8, 2, true, 4>
      <<<dim3(2048, 4), dim3(64), 0, stream>>>(A, wp4, s4, t4, B, 8);

  // L5: bconv (CW=8, 8x8, OC=512) B->A [128,8,8,16]    grid 128*4=512 x 8
  bconv_kernel<8, 8, 8, 8, 2, false, 4>
      <<<dim3(512, 8), dim3(64), 0, stream>>>(B, wp5, s5, t5, A, 16);

  // L6: bconv+pool (CW=16, 8x8) A->B [128,4,4,16]      grid 128*4=512 x 8
  bconv_kernel<16, 8, 8, 8, 2, true, 2>
      <<<dim3(512, 8), dim3(64), 0, stream>>>(A, wp6, s6, t6, B, 16);

  // L7: conv7 + bn7 + log_softmax -> out [128,10]
  conv7_kernel<<<dim3(128), dim3(64), 0, stream>>>(B, wp7, s7, t7, out);
}

// Round 5
// 322.396 us; speedup vs baseline: 1.3358x; 1.0199x over previous
//
#include <hip/hip_runtime.h>
#include <cstdint>
#include <math.h>

#define NB 128  // batch size

// ---------------------------------------------------------------------------
// Weight packing.
// Layers 2-6: layout wp[ocg][tap][cw][oc64]  (oc64 = lane) so a wave's 64
//   weight words per (tap,cw) are one coalesced dword load.
// Layer 7:    layout wp[o][tap][cw] (conv7 consumes linearly).
// Layer 1:    wp1[(ocg*27+t)*2+half] : 64-bit sign mask per (ocg,tap),
//             bit o = (w1[ocg*64+o][tap] >= 0)  (o = half*32+b)
// bit (c%32) of word = (w[o][c][kh][kw] >= 0)
// ---------------------------------------------------------------------------
__global__ void pack_all_kernel(
    const float* __restrict__ w1,
    const float* __restrict__ w2, const float* __restrict__ w3,
    const float* __restrict__ w4, const float* __restrict__ w5,
    const float* __restrict__ w6, const float* __restrict__ w7,
    uint32_t* __restrict__ wp1,
    uint32_t* __restrict__ wp2, uint32_t* __restrict__ wp3,
    uint32_t* __restrict__ wp4, uint32_t* __restrict__ wp5,
    uint32_t* __restrict__ wp6, uint32_t* __restrict__ wp7) {
  int i = blockIdx.x * 256 + threadIdx.x;
  if (i >= 145516) return;
  if (i >= 145408) {  // conv1 sign masks
    int j = i - 145408;          // 0..107
    int ocg = j / 54, rem = j % 54, t = rem >> 1, half = rem & 1;
    uint32_t word = 0;
    for (int b = 0; b < 32; ++b)
      word |= ((w1[(ocg * 64 + half * 32 + b) * 27 + t] >= 0.0f) ? 1u : 0u) << b;
    wp1[(ocg * 27 + t) * 2 + half] = word;
    return;
  }
  const float* w; uint32_t* wp; int C, KHW; bool nl = true;
  if (i < 4608)        { w = w2; wp = wp2; C = 128; KHW = 9; }
  else if (i < 13824)  { i -= 4608;   w = w3; wp = wp3; C = 128; KHW = 9; }
  else if (i < 32256)  { i -= 13824;  w = w4; wp = wp4; C = 256; KHW = 9; }
  else if (i < 69120)  { i -= 32256;  w = w5; wp = wp5; C = 256; KHW = 9; }
  else if (i < 142848) { i -= 69120;  w = w6; wp = wp6; C = 512; KHW = 9; }
  else                 { i -= 142848; w = w7; wp = wp7; C = 512; KHW = 16; nl = false; }
  int Cw = C >> 5;
  int cw = i % Cw;
  int rest = i / Cw;
  int t = rest % KHW;
  int o = rest / KHW;
  uint32_t word = 0;
  for (int b = 0; b < 32; ++b)
    word |= ((w[(o * C + cw * 32 + b) * KHW + t] >= 0.0f) ? 1u : 0u) << b;
  if (nl) wp[(((o >> 6) * KHW + t) * Cw + cw) * 64 + (o & 63)] = word;
  else    wp[(o * KHW + t) * Cw + cw] = word;
}

// per-lane select from a wave-uniform 64-bit mask (lowers to mask-as-VCC)
__device__ __forceinline__ bool lane_bit(uint64_t m, int lane) {
#if __has_builtin(__builtin_amdgcn_inverse_ballot_w64)
  (void)lane;
  return __builtin_amdgcn_inverse_ballot_w64(m);
#else
  return (m >> lane) & 1;
#endif
}

// ---------------------------------------------------------------------------
// Conv1, oc-in-lane weight-stationary: lane = oc in ocg (blockIdx.y of 2),
// wave covers R rows x PC cols of one image. Weights = 27 uniform 64-bit
// sign masks (s_load); acts = wave-uniform scalar f32 loads (halo read once).
// MAC: acc += maskbit ? -xd : xd in f64 (accumulation order ic,kh,kw asc ==
// previous passing version -> bit-identical sums; downstream is chaotic in
// the sign bits so conv1 must match the f64 numpy reference).
// Epilogue: bn sign in f64 (exact), __ballot packs 64 sign bits -> 2 words.
// ---------------------------------------------------------------------------
template <int PC, int R>
__global__ __launch_bounds__(64, 6) void conv1_kernel(
    const float* __restrict__ x, const uint32_t* __restrict__ wp1,
    const float* __restrict__ bs, const float* __restrict__ bt,
    uint32_t* __restrict__ out) {
  const int lane = threadIdx.x;
  const int ocg = blockIdx.y;
  const int cpr = 32 / PC;
  const int c = blockIdx.x;
  const int cg = c % cpr;
  const int rg = (c / cpr) % (32 / R);
  const int n  = c / (cpr * (32 / R));
  const int y0 = rg * R, x0 = cg * PC;

  double acc[R * PC];
#pragma unroll
  for (int p = 0; p < R * PC; ++p) acc[p] = 0.0;

  const uint64_t* wm64 = (const uint64_t*)wp1;
  for (int ic = 0; ic < 3; ++ic) {
    uint64_t wm[9];
#pragma unroll
    for (int t = 0; t < 9; ++t) wm[t] = wm64[ocg * 27 + ic * 9 + t];  // uniform
#pragma unroll
    for (int ey = -1; ey <= R; ++ey) {
      const int y = y0 + ey;
      if (y < 0 || y >= 32) continue;          // uniform branch
#pragma unroll
      for (int ex = -1; ex <= PC; ++ex) {
        const int xx = x0 + ex;
        if (xx < 0 || xx >= 32) continue;      // uniform branch
        const double xd = (double)x[((n * 3 + ic) * 32 + y) * 32 + xx];  // s_load
#pragma unroll
        for (int r = 0; r < R; ++r) {
          const int kh = ey - r + 1;           // compile-time after unroll
          if (kh < 0 || kh > 2) continue;
#pragma unroll
          for (int kw = 0; kw < 3; ++kw) {
            const int pxo = ex - kw + 1;       // compile-time
            if (pxo < 0 || pxo >= PC) continue;
            const bool neg = lane_bit(wm[kh * 3 + kw], lane) == false;
            // mask bit 1 == weight >= 0 -> +x ; bit 0 -> -x
            acc[r * PC + pxo] += neg ? -xd : xd;
          }
        }
      }
    }
  }

  const double sd = (double)bs[ocg * 64 + lane];
  const double td = (double)bt[ocg * 64 + lane];
  uint64_t bal[R * PC];
#pragma unroll
  for (int r = 0; r < R; ++r)
#pragma unroll
    for (int pxo = 0; pxo < PC; ++pxo) {
      double v = acc[r * PC + pxo] * sd + td;
      bal[r * PC + pxo] = __ballot(v >= 0.0);
    }
  if (lane == 0) {
#pragma unroll
    for (int r = 0; r < R; ++r)
#pragma unroll
      for (int pxo = 0; pxo < PC; ++pxo) {
        const int p = ((n * 32 + (y0 + r)) * 32 + (x0 + pxo));
        uint32_t* o = out + p * 4 + ocg * 2;
        uint64_t m = bal[r * PC + pxo];
        o[0] = (uint32_t)m; o[1] = (uint32_t)(m >> 32);
      }
  }
}

// ---------------------------------------------------------------------------
// Binary conv 3x3 pad=1 — oc-in-lane, weight-stationary.
//   lane = oc in the wave's 64-oc group (blockIdx.y); 1 wave = R x PC pixels.
// Weights: 9*CWP lane-private VGPRs per pass (CW/CWP passes, splits VGPR
//   pressure for CW=16). Acts: wave-uniform -> scalar loads. Inner op:
//   v_xor(s,v) + accumulating v_bcnt. Border taps: uniform branches.
// Epilogue: bn sign in f64 (exact: s*dot has 24b x <=14b mantissas);
//   __ballot packs 64 sign bits -> 2 words. POOL: OR of the 2x2 ballots.
// ---------------------------------------------------------------------------
template <int CW, int CWP, int H, int W, int PC, int R, bool POOL, int MINW>
__global__ __launch_bounds__(64, MINW) void bconv_kernel(
    const uint32_t* __restrict__ act, const uint32_t* __restrict__ wpk,
    const float* __restrict__ bs, const float* __restrict__ bt,
    uint32_t* __restrict__ out, int OCW) {
  static_assert(CW % CWP == 0, "");
  const int lane = threadIdx.x;
  const int ocg = blockIdx.y;
  const int cpr = W / PC;
  const int c = blockIdx.x;
  const int cg = c % cpr;
  const int rg = (c / cpr) % (H / R);
  const int n  = c / (cpr * (H / R));
  const int y0 = rg * R, x0 = cg * PC;

  int acc[R * PC];
#pragma unroll
  for (int p = 0; p < R * PC; ++p) acc[p] = 0;

#pragma unroll
  for (int pass = 0; pass < CW / CWP; ++pass) {
    // stationary weights for this pass: 9*CWP lane-private words
    uint32_t wreg[9 * CWP];
#pragma unroll
    for (int t = 0; t < 9; ++t)
#pragma unroll
      for (int cw = 0; cw < CWP; ++cw)
        wreg[t * CWP + cw] = wpk[(((ocg * 9) + t) * CW + pass * CWP + cw) * 64 + lane];

#pragma unroll
    for (int ry = -1; ry <= R; ++ry) {
      const int y = y0 + ry;
      if (y < 0 || y >= H) continue;          // uniform branch
#pragma unroll
      for (int cc = -1; cc <= PC; ++cc) {
        const int x = x0 + cc;
        if (x < 0 || x >= W) continue;        // uniform branch
        const uint32_t* ap = act + ((n * H + y) * W + x) * CW + pass * CWP;
        uint32_t av[CWP];
#pragma unroll
        for (int cw = 0; cw < CWP; ++cw) av[cw] = ap[cw];  // uniform -> s_load
#pragma unroll
        for (int r = 0; r < R; ++r) {
          const int kh = ry - r + 1;          // compile-time after unroll
          if (kh < 0 || kh > 2) continue;
#pragma unroll
          for (int kw = 0; kw < 3; ++kw) {
            const int pxo = cc - kw + 1;      // compile-time
            if (pxo < 0 || pxo >= PC) continue;
#pragma unroll
            for (int cw = 0; cw < CWP; ++cw)
              acc[r * PC + pxo] += __popc(av[cw] ^ wreg[(kh * 3 + kw) * CWP + cw]);
          }
        }
      }
    }
  }

  // --- epilogue: bn sign (f64, exact) -> ballot-packed words ---
  const double sd = (double)bs[ocg * 64 + lane];
  const double td = (double)bt[ocg * 64 + lane];
  if (!POOL) {
    uint64_t bal[R * PC];
#pragma unroll
    for (int r = 0; r < R; ++r)
#pragma unroll
      for (int pxo = 0; pxo < PC; ++pxo) {
        const int y = y0 + r, x = x0 + pxo;
        const int nv = CW * (3 - (y == 0) - (y == H - 1)) * (3 - (x == 0) - (x == W - 1));
        double v = (double)(32 * nv - 2 * acc[r * PC + pxo]) * sd + td;
        bal[r * PC + pxo] = __ballot(v >= 0.0);
      }
    if (lane == 0) {
#pragma unroll
      for (int r = 0; r < R; ++r)
#pragma unroll
        for (int pxo = 0; pxo < PC; ++pxo) {
          uint32_t* o = out + ((n * H + (y0 + r)) * W + (x0 + pxo)) * OCW + ocg * 2;
          uint64_t m = bal[r * PC + pxo];
          o[0] = (uint32_t)m; o[1] = (uint32_t)(m >> 32);
        }
    }
  } else {
    static_assert(!POOL || R == 2, "pool needs row pairs");
    uint64_t pooled[PC / 2];
#pragma unroll
    for (int c2 = 0; c2 < PC / 2; ++c2) pooled[c2] = 0;
#pragma unroll
    for (int r = 0; r < R; ++r)
#pragma unroll
      for (int pxo = 0; pxo < PC; ++pxo) {
        const int y = y0 + r, x = x0 + pxo;
        const int nv = CW * (3 - (y == 0) - (y == H - 1)) * (3 - (x == 0) - (x == W - 1));
        double v = (double)(32 * nv - 2 * acc[r * PC + pxo]) * sd + td;
        pooled[pxo >> 1] |= __ballot(v >= 0.0);
      }
    if (lane == 0) {
#pragma unroll
      for (int c2 = 0; c2 < PC / 2; ++c2) {
        const int yo = y0 >> 1, xo = (x0 >> 1) + c2;
        uint32_t* o = out + ((n * (H / 2) + yo) * (W / 2) + xo) * OCW + ocg * 2;
        o[0] = (uint32_t)pooled[c2]; o[1] = (uint32_t)(pooled[c2] >> 32);
      }
    }
  }
}

// ---------------------------------------------------------------------------
// Conv7 (4x4 VALID, K=512*16=8192 = 256 words) + bn7 + log_softmax (double)
// One block (1 wave) per image.
// ---------------------------------------------------------------------------
__global__ __launch_bounds__(64) void conv7_kernel(
    const uint32_t* __restrict__ act, const uint32_t* __restrict__ wp,
    const float* __restrict__ bs, const float* __restrict__ bt,
    float* __restrict__ out) {
  int n = blockIdx.x;
  int lane = threadIdx.x;
  const uint32_t* a = act + n * 256;
  __shared__ double logits[10];
  for (int o = 0; o < 10; ++o) {
    int acc = 0;
    for (int w = lane; w < 256; w += 64) acc += __popc(a[w] ^ wp[o * 256 + w]);
    for (int off = 32; off > 0; off >>= 1) acc += __shfl_down(acc, off, 64);
    if (lane == 0) {
      double dotd = (double)(8192 - 2 * acc);
      logits[o] = dotd * (double)bs[o] + (double)bt[o];
    }
  }
  __syncthreads();
  if (lane == 0) {
    double m = logits[0];
    for (int o = 1; o < 10; ++o) m = fmax(m, logits[o]);
    double s = 0.0;
    for (int o = 0; o < 10; ++o) s += exp(logits[o] - m);
    double lse = log(s);
    for (int o = 0; o < 10; ++o) out[n * 10 + o] = (float)(logits[o] - m - lse);
  }
}

// ---------------------------------------------------------------------------
extern "C" void kernel_launch(void* const* d_in, const int* in_sizes, int n_in,
                              void* d_out, int out_size, void* d_ws, size_t ws_size,
                              hipStream_t stream) {
  const float* x  = (const float*)d_in[0];
  const float* w1 = (const float*)d_in[1];
  const float* w2 = (const float*)d_in[2];
  const float* w3 = (const float*)d_in[3];
  const float* w4 = (const float*)d_in[4];
  const float* w5 = (const float*)d_in[5];
  const float* w6 = (const float*)d_in[6];
  const float* w7 = (const float*)d_in[7];
  const float* s1 = (const float*)d_in[8];  const float* t1 = (const float*)d_in[9];
  const float* s2 = (const float*)d_in[10]; const float* t2 = (const float*)d_in[11];
  const float* s3 = (const float*)d_in[12]; const float* t3 = (const float*)d_in[13];
  const float* s4 = (const float*)d_in[14]; const float* t4 = (const float*)d_in[15];
  const float* s5 = (const float*)d_in[16]; const float* t5 = (const float*)d_in[17];
  const float* s6 = (const float*)d_in[18]; const float* t6 = (const float*)d_in[19];
  const float* s7 = (const float*)d_in[20]; const float* t7 = (const float*)d_in[21];
  float* out = (float*)d_out;

  uint32_t* ws = (uint32_t*)d_ws;
  uint32_t* A   = ws;                 // 524288 words (2 MB) ping
  uint32_t* B   = ws + 524288;        // 524288 words pong
  uint32_t* wp2 = ws + 1048576;       // 2*9*4*64   = 4608
  uint32_t* wp3 = wp2 + 4608;         // 4*9*4*64   = 9216
  uint32_t* wp4 = wp3 + 9216;         // 4*9*8*64   = 18432
  uint32_t* wp5 = wp4 + 18432;        // 8*9*8*64   = 36864
  uint32_t* wp6 = wp5 + 36864;        // 8*9*16*64  = 73728
  uint32_t* wp7 = wp6 + 73728;        // 10*16*16   = 2560
  uint32_t* wp1 = wp7 + 2560;         // 2*27*2     = 108   (8B-aligned)

  // pack all weights in one dispatch (ws re-poisoned every call -> repack)
  pack_all_kernel<<<dim3(569), dim3(256), 0, stream>>>(
      w1, w2, w3, w4, w5, w6, w7, wp1, wp2, wp3, wp4, wp5, wp6, wp7);

  // L1: conv1(f64, oc-in-lane) + bn1 + sign -> A [128,32,32,4]
  conv1_kernel<8, 2><<<dim3(8192, 2), dim3(64), 0, stream>>>(x, wp1, s1, t1, A);

  // L2: bconv+pool (CW=4, 32x32) A->B [128,16,16,4]
  bconv_kernel<4, 4, 32, 32, 8, 2, true, 6>
      <<<dim3(8192, 2), dim3(64), 0, stream>>>(A, wp2, s2, t2, B, 4);

  // L3: bconv (CW=4, 16x16, OC=256) B->A [128,16,16,8]
  bconv_kernel<4, 4, 16, 16, 16, 1, false, 6>
      <<<dim3(2048, 4), dim3(64), 0, stream>>>(B, wp3, s3, t3, A, 8);

  // L4: bconv+pool (CW=8, 16x16) A->B [128,8,8,8]
  bconv_kernel<8, 8, 16, 16, 8, 2, true, 4>
      <<<dim3(2048, 4), dim3(64), 0, stream>>>(A, wp4, s4, t4, B, 8);

  // L5: bconv (CW=8, 8x8, OC=512) B->A [128,8,8,16]
  bconv_kernel<8, 8, 8, 8, 8, 2, false, 4>
      <<<dim3(512, 8), dim3(64), 0, stream>>>(B, wp5, s5, t5, A, 16);

  // L6: bconv+pool (CW=16 in 2 passes of 8) A->B [128,4,4,16]
  bconv_kernel<16, 8, 8, 8, 8, 2, true, 4>
      <<<dim3(512, 8), dim3(64), 0, stream>>>(A, wp6, s6, t6, B, 16);

  // L7: conv7 + bn7 + log_softmax -> out [128,10]
  conv7_kernel<<<dim3(128), dim3(64), 0, stream>>>(B, wp7, s7, t7, out);
}